// Round 5
// baseline (116.424 us; speedup 1.0000x reference)
//
#include <hip/hip_runtime.h>

// AllGNN: out = ((adj @ (x@W_in + b_in)) / (rowsum(adj)+1)) @ W_cls + b_cls
// N=12000, IN_CH=256, HID=64, N_CLS=40. adj binary f32, ~0.2% dense (576 MB).
// Two-phase aggregation (Phase A: pure adj stream, nz -> LDS lists; Phase B:
// pipelined L2 gathers). R5: rotating 4-deep cross-group prefetch (steady
// vmcnt(3), no group-boundary drains) + wave-level nz skip.

#define NN     12000
#define INCH   256
#define HID    64
#define NCLS   40
#define NCHUNK ((NN + 255) / 256)   // 47
#define CAP    512                   // per-wave nz list capacity (E[nz]~6)

typedef float f4 __attribute__((ext_vector_type(4)));

// ---------------- Kernel 1: h = x @ W_in + b_in  (4 rows per wave) ---------
__global__ __launch_bounds__(256) void fc_in_kernel(
    const float* __restrict__ x, const float* __restrict__ W_in,
    const float* __restrict__ b_in, float* __restrict__ h)
{
    const int lane = threadIdx.x & 63;
    const int w    = threadIdx.x >> 6;
    int rbase = (blockIdx.x * 4 + w) * 4;            // 750 blocks * 16 rows
    rbase = __builtin_amdgcn_readfirstlane(rbase);   // SGPR base -> s_load x

    const float* __restrict__ xr = x + (size_t)rbase * INCH;
    const float  b = b_in[lane];                     // lane owns hid channel
    float acc0 = b, acc1 = b, acc2 = b, acc3 = b;

    #pragma unroll 8
    for (int c = 0; c < INCH; ++c) {
        float wv = W_in[c * HID + lane];             // reused x4 rows
        acc0 = fmaf(xr[c],            wv, acc0);     // uniform -> scalar ld
        acc1 = fmaf(xr[INCH + c],     wv, acc1);
        acc2 = fmaf(xr[2 * INCH + c], wv, acc2);
        acc3 = fmaf(xr[3 * INCH + c], wv, acc3);
    }
    float* hp = h + (size_t)rbase * HID + lane;
    hp[0 * HID] = acc0;
    hp[1 * HID] = acc1;
    hp[2 * HID] = acc2;
    hp[3 * HID] = acc3;
}

// ------- Kernel 2: fused deg + sparse aggregation + classifier head --------
// One BLOCK per adjacency row; 4 waves stride chunks; lane owns hid channel.
__global__ __launch_bounds__(256) void gnn_agg_kernel(
    const float* __restrict__ adj, const float* __restrict__ h,
    const float* __restrict__ W_cls, const float* __restrict__ b_cls,
    float* __restrict__ out)
{
    const int lane = threadIdx.x & 63;
    const int w    = threadIdx.x >> 6;          // wave id 0..3
    const int row  = blockIdx.x;

    __shared__ int   s_cnt[4];
    __shared__ int   s_col[4][CAP];
    __shared__ float s_val[4][CAP];
    __shared__ float s_acc[4][HID];
    __shared__ float s_deg[4];

    if (lane == 0) s_cnt[w] = 0;                // per-wave; same-wave DS order

    const float* __restrict__ arow = adj + (size_t)row * NN;
    const int bl = lane * 4;
    float deg = 0.0f;

    // load chunk ci (256 cols); OOB (partial chunk 46 / ci>=NCHUNK) -> zeros
    auto loadc = [&](int ci) -> f4 {
        const int base = ci * 256 + bl;
        f4 v = {0.f, 0.f, 0.f, 0.f};
        if (base + 4 <= NN)
            v = __builtin_nontemporal_load(reinterpret_cast<const f4*>(arow + base));
        return v;
    };
    // Phase A scan: LDS-only side effects -> adj stream never waits on gathers
    auto scan = [&](f4 v, int ci) {
        float s = (v[0] + v[1]) + (v[2] + v[3]);
        deg += s;
        if (__any(s != 0.0f)) {                 // ~39% of wave-chunks
            const int col = ci * 256 + bl;
            #pragma unroll
            for (int i = 0; i < 4; ++i) {
                if (v[i] != 0.0f) {
                    int idx = atomicAdd(&s_cnt[w], 1);
                    if (idx < CAP) { s_col[w][idx] = col + i; s_val[w][idx] = v[i]; }
                }
            }
        }
    };

    // wave w owns chunk slots k=0..11 (chunk = w + 4k; slot>=12 -> masked off).
    // Rotating 4-deep prefetch: scan(v_i) then reload v_i from 4 slots ahead;
    // steady-state vmcnt(3), no group-boundary drain.
    f4 v0 = loadc(w);
    f4 v1 = loadc(w + 4);
    f4 v2 = loadc(w + 8);
    f4 v3 = loadc(w + 12);
    #pragma unroll 1
    for (int k = 0; k < 12; k += 4) {
        const int c = w + k * 4;
        scan(v0, c);      v0 = loadc(c + 16);
        scan(v1, c + 4);  v1 = loadc(c + 20);
        scan(v2, c + 8);  v2 = loadc(c + 24);
        scan(v3, c + 12); v3 = loadc(c + 28);
    }

    // Phase B: drain this wave's nz list, 4 independent gathers in flight
    float acc = 0.0f;
    int n = s_cnt[w];                            // same-wave DS ordering
    n = (n < CAP) ? n : CAP;
    int i = 0;
    for (; i + 4 <= n; i += 4) {
        int   c0 = s_col[w][i],     c1 = s_col[w][i + 1];
        int   c2 = s_col[w][i + 2], c3 = s_col[w][i + 3];
        float a0 = s_val[w][i],     a1 = s_val[w][i + 1];
        float a2 = s_val[w][i + 2], a3 = s_val[w][i + 3];
        float h0 = h[(size_t)c0 * HID + lane];
        float h1 = h[(size_t)c1 * HID + lane];
        float h2 = h[(size_t)c2 * HID + lane];
        float h3 = h[(size_t)c3 * HID + lane];
        acc = fmaf(a0, h0, fmaf(a1, h1, fmaf(a2, h2, fmaf(a3, h3, acc))));
    }
    for (; i < n; ++i)
        acc = fmaf(s_val[w][i], h[(size_t)s_col[w][i] * HID + lane], acc);

    // wave-reduce deg, publish partials
    #pragma unroll
    for (int off = 32; off; off >>= 1) deg += __shfl_xor(deg, off);
    s_acc[w][lane] = acc;
    if (lane == 0) s_deg[w] = deg;
    __syncthreads();

    if (w == 0) {
        float a  = (s_acc[0][lane] + s_acc[1][lane])
                 + (s_acc[2][lane] + s_acc[3][lane]);
        float dt = (s_deg[0] + s_deg[1]) + (s_deg[2] + s_deg[3]);
        float agg = a * __frcp_rn(dt + 1.0f);

        const int cl = (lane < NCLS) ? lane : 0;   // clamp, no divergence
        float o = b_cls[cl];
        #pragma unroll 8
        for (int k = 0; k < HID; ++k) {
            float av = __shfl(agg, k);
            o = fmaf(av, W_cls[k * NCLS + cl], o);
        }
        if (lane < NCLS) out[(size_t)row * NCLS + lane] = o;
    }
}

extern "C" void kernel_launch(void* const* d_in, const int* in_sizes, int n_in,
                              void* d_out, int out_size, void* d_ws, size_t ws_size,
                              hipStream_t stream)
{
    const float* x     = (const float*)d_in[0];
    const float* adj   = (const float*)d_in[1];
    const float* W_in  = (const float*)d_in[2];
    const float* b_in  = (const float*)d_in[3];
    const float* W_cls = (const float*)d_in[4];
    const float* b_cls = (const float*)d_in[5];
    float* out = (float*)d_out;
    float* h   = (float*)d_ws;               // 12000*64*4 = 3 MB scratch

    fc_in_kernel<<<NN / 16, 256, 0, stream>>>(x, W_in, b_in, h);
    gnn_agg_kernel<<<NN, 256, 0, stream>>>(adj, h, W_cls, b_cls, out);
}